// Round 4
// baseline (107.836 us; speedup 1.0000x reference)
//
#include <hip/hip_runtime.h>

// ---------------------------------------------------------------------------
// TextureAnalysisModule: x (16,3,1024,1024) f32
//  k_score   : per-(patch,slice) |dx|,|dy| partial sums
//              (f32 row-group tree -> f64 accumulate; 8-row unrolled loads)
//  k_rankall : reduce 48 slices -> 1024 scores (redundant per block) +
//              stable rank-by-counting -> top9/bot9 indices
//  k_output  : gather patches -> R -> H (x-bilerp) -> U (y-bilerp) -> 3x3 SRM
//  out: (2,16,3,224,224) f32
// ---------------------------------------------------------------------------

#define NSLICE 48
#define IMG    1048576
#define TILE   8

// --- K1: one block per (patch-row, slice); contiguous 32x1024 strip. -------
__global__ __launch_bounds__(256) void k_score(const float* __restrict__ x,
                                               double* __restrict__ part) {
  const int ph = blockIdx.x;   // patch row 0..31
  const int s  = blockIdx.y;   // slice 0..47
  const int t  = threadIdx.x;
  const float* base = x + (size_t)s * IMG + (size_t)ph * 32768 + 4 * t;

  double s1x = 0.0, s2x = 0.0, s1y = 0.0, s2y = 0.0;
  const bool has_d3 = (t & 7) != 7;   // col 4t+3 is not a patch boundary

#define LD(r) (*(const float4*)(base + (size_t)(r) * 1024))
  // f32 tree-sum per row, single f64 add per quantity per row.
#define DX(v) { float nx = __shfl_down((v).x, 1);                              \
    float d0 = fabsf((v).y-(v).x), d1 = fabsf((v).z-(v).y),                    \
          d2 = fabsf((v).w-(v).z);                                             \
    float d3 = has_d3 ? fabsf(nx-(v).w) : 0.f;                                 \
    s1x += (double)((d0+d1)+(d2+d3));                                          \
    s2x += (double)((d0*d0+d1*d1)+(d2*d2+d3*d3)); }
#define DY(a,b) { float e0 = fabsf((b).x-(a).x), e1 = fabsf((b).y-(a).y),      \
                        e2 = fabsf((b).z-(a).z), e3 = fabsf((b).w-(a).w);      \
    s1y += (double)((e0+e1)+(e2+e3));                                          \
    s2y += (double)((e0*e0+e1*e1)+(e2*e2+e3*e3)); }

  float4 v0 = LD(0);
  for (int r = 0; r < 32; r += 8) {
    float4 w1 = LD(r + 1), w2 = LD(r + 2), w3 = LD(r + 3), w4 = LD(r + 4);
    float4 w5 = LD(r + 5), w6 = LD(r + 6), w7 = LD(r + 7);
    float4 w8;
    const bool more = (r + 8 < 32);
    if (more) w8 = LD(r + 8);
    DX(v0); DX(w1); DX(w2); DX(w3); DX(w4); DX(w5); DX(w6); DX(w7);
    DY(v0, w1); DY(w1, w2); DY(w2, w3); DY(w3, w4);
    DY(w4, w5); DY(w5, w6); DY(w6, w7);
    if (more) { DY(w7, w8); v0 = w8; }
  }
#undef LD
#undef DX
#undef DY

  // reduce within each 8-lane group (one patch per group)
#pragma unroll
  for (int off = 4; off > 0; off >>= 1) {
    s1x += __shfl_down(s1x, off, 8);
    s2x += __shfl_down(s2x, off, 8);
    s1y += __shfl_down(s1y, off, 8);
    s2y += __shfl_down(s2y, off, 8);
  }
  if ((t & 7) == 0) {
    const int p = ph * 32 + (t >> 3);
    part[(size_t)(0 * NSLICE + s) * 1024 + p] = s1x;
    part[(size_t)(1 * NSLICE + s) * 1024 + p] = s2x;
    part[(size_t)(2 * NSLICE + s) * 1024 + p] = s1y;
    part[(size_t)(3 * NSLICE + s) * 1024 + p] = s2y;
  }
}

// --- K2: fused finalize + stable rank. 32 blocks; each block redundantly ---
// computes all 1024 scores (L2-hot), then ranks its 32 candidates.
// sel[0..8] = rich (ranks 1015..1023 asc), sel[9..17] = poor (ranks 0..8 asc).
__global__ __launch_bounds__(256) void k_rankall(const double* __restrict__ part,
                                                 int* __restrict__ sel) {
  __shared__ double sc[1024];
  const int t = threadIdx.x;

  double S[4][4];   // [pi][q], p = t + pi*256
#pragma unroll
  for (int pi = 0; pi < 4; ++pi)
#pragma unroll
    for (int q = 0; q < 4; ++q) S[pi][q] = 0.0;

  for (int s = 0; s < NSLICE; ++s) {
#pragma unroll
    for (int q = 0; q < 4; ++q) {
      const double* b = part + (size_t)(q * NSLICE + s) * 1024 + t;
#pragma unroll
      for (int pi = 0; pi < 4; ++pi) S[pi][q] += b[pi * 256];
    }
  }

  const double N = 47616.0;  // 16*3*32*31
#pragma unroll
  for (int pi = 0; pi < 4; ++pi) {
    double mx = S[pi][0] / N, my = S[pi][2] / N;
    double vx = (S[pi][1] - S[pi][0] * S[pi][0] / N) / (N - 1.0);
    double vy = (S[pi][3] - S[pi][2] * S[pi][2] / N) / (N - 1.0);
    sc[t + pi * 256] = 0.25 * (mx + my) * (vx + vy);
  }
  __syncthreads();

  const int c = blockIdx.x * 32 + (t >> 3);
  const double mine = sc[c];
  int rank = 0;
  for (int j = (t & 7); j < 1024; j += 8) {
    double vj = sc[j];
    rank += (vj < mine) || (vj == mine && j < c);
  }
#pragma unroll
  for (int off = 4; off > 0; off >>= 1) rank += __shfl_down(rank, off, 8);
  if ((t & 7) == 0) {
    if (rank < 9)          sel[9 + rank]    = c;
    else if (rank >= 1015) sel[rank - 1015] = c;
  }
}

// --- K3: one block per (image, 8-row output strip). ------------------------
// R (<=6x96 src rows) -> H (x-bilerp, <=6x224) -> U (y-bilerp, 10x224)
// -> 3x3 SRM conv with zero padding.
__global__ __launch_bounds__(256) void k_output(const float* __restrict__ x,
                                                const int* __restrict__ sel,
                                                float* __restrict__ out) {
  const int ty  = blockIdx.x;              // 0..27
  const int blk = blockIdx.y;              // 0..95 = set*48 + (b*3+c)
  const int set = blk / 48;
  const int bc  = blk % 48;
  const int y0  = ty * TILE;

  __shared__ int   i0t[224];
  __shared__ float frt[224];
  __shared__ float R[6][97];
  __shared__ float H[6][224];
  __shared__ float U[10][224];
  __shared__ int   selm[9];
  const int t = threadIdx.x;

  if (t < 9) selm[t] = sel[set * 9 + t];
  if (t < 224) {
    // src coord = (t+0.5)*96/224 - 0.5 = (3t-2)/7 ; edge renorm == clamp
    int num = 3 * t - 2;
    int i0, fr7;
    if (num < 0) { i0 = 0; fr7 = 0; }
    else {
      i0 = num / 7; fr7 = num - i0 * 7;
      if (i0 >= 95) { i0 = 95; fr7 = 0; }
    }
    i0t[t] = i0;
    frt[t] = (float)fr7 * (1.0f / 7.0f);
  }
  __syncthreads();

  const int Ylo   = max(y0 - 1, 0);
  const int Yhi   = min(y0 + TILE, 223);
  const int sy_lo = i0t[Ylo];
  const int sy_hi = min(i0t[Yhi] + 1, 95);
  const int nrows = sy_hi - sy_lo + 1;     // <= 6

  // gather source rows
  const float* src = x + (size_t)bc * IMG;
  for (int idx = t; idx < nrows * 96; idx += 256) {
    int ry = idx / 96, xx = idx - ry * 96;
    int sy = sy_lo + ry;
    int gr = sy >> 5, i = sy & 31;
    int gc = xx >> 5, j = xx & 31;
    int pidx = selm[gr * 3 + gc];
    R[ry][xx] = src[(size_t)((pidx >> 5) * 32 + i) * 1024 + (pidx & 31) * 32 + j];
  }
  __syncthreads();

  // horizontal bilinear: H[r][X]
  for (int idx = t; idx < nrows * 224; idx += 256) {
    int r = idx / 224, X = idx - r * 224;
    int ix0 = i0t[X], ix1 = min(ix0 + 1, 95);
    float fx = frt[X];
    float a = R[r][ix0], b = R[r][ix1];
    H[r][X] = a + fx * (b - a);
  }
  __syncthreads();

  // vertical bilinear: U[yy][X], Y = y0-1+yy for yy in [0,10)
  for (int idx = t; idx < 10 * 224; idx += 256) {
    int yy = idx / 224, X = idx - yy * 224;
    int Y = y0 - 1 + yy;
    if ((unsigned)Y < 224u) {
      int a = i0t[Y] - sy_lo;
      int b = min(i0t[Y] + 1, 95) - sy_lo;
      float fy = frt[Y];
      float h0 = H[a][X], h1 = H[b][X];
      U[yy][X] = h0 + fy * (h1 - h0);
    }
  }
  __syncthreads();

  // 3x3 SRM conv (zero padding)
  const float F[3][3] = {{-1.f, 3.f, -1.f}, {3.f, -8.f, 3.f}, {-1.f, 3.f, -1.f}};
  float* o = out + (size_t)blk * (224 * 224);
  for (int idx = t; idx < TILE * 224; idx += 256) {
    int yy = idx / 224;
    int xx = idx - yy * 224;
    int y  = y0 + yy;
    float acc = 0.f;
#pragma unroll
    for (int dy = 0; dy < 3; ++dy) {
      int Y = y + dy - 1;
      if ((unsigned)Y >= 224u) continue;
      const float* Ur = U[yy + dy];        // row Y = y0-1+(yy+dy)
#pragma unroll
      for (int dx = 0; dx < 3; ++dx) {
        int X = xx + dx - 1;
        if ((unsigned)X >= 224u) continue;
        acc += F[dy][dx] * Ur[X];
      }
    }
    o[(size_t)y * 224 + xx] = acc;
  }
}

extern "C" void kernel_launch(void* const* d_in, const int* in_sizes, int n_in,
                              void* d_out, int out_size, void* d_ws, size_t ws_size,
                              hipStream_t stream) {
  const float* x = (const float*)d_in[0];
  float* out = (float*)d_out;

  double* part = (double*)d_ws;                      // 4*48*1024*8 = 1.5 MB
  int*    sel  = (int*)((char*)d_ws + 1572864);      // 72 B

  k_score  <<<dim3(32, 48), 256, 0, stream>>>(x, part);
  k_rankall<<<32, 256, 0, stream>>>(part, sel);
  k_output <<<dim3(28, 96), 256, 0, stream>>>(x, sel, out);
}

// Round 5
// 67.974 us; speedup vs baseline: 1.5864x; 1.5864x over previous
//
#include <hip/hip_runtime.h>

// ---------------------------------------------------------------------------
// TextureAnalysisModule: x (16,3,1024,1024) f32
//  k_score    : per-(patch,slice) |dx|,|dy| partial sums (f64, no atomics)
//  k_finalize : one block per patch; 192 parallel loads + shfl tree
//  k_rank     : stable rank-by-counting, scatter top9/bot9 indices
//  k_output   : gather patches -> R -> H (x-bilerp) -> U (y-bilerp) -> 3x3 SRM
//  out: (2,16,3,224,224) f32
// ---------------------------------------------------------------------------

#define NSLICE 48
#define IMG    1048576
#define TILE   8

// --- K1: one block per (patch-row, slice); contiguous 32x1024 strip. -------
// (round-3 verbatim: measured within the 76.6 us total)
__global__ __launch_bounds__(256) void k_score(const float* __restrict__ x,
                                               double* __restrict__ part) {
  const int ph = blockIdx.x;   // patch row 0..31
  const int s  = blockIdx.y;   // slice 0..47
  const int t  = threadIdx.x;
  const float* base = x + (size_t)s * IMG + (size_t)ph * 32768 + 4 * t;

  double s1x = 0.0, s2x = 0.0, s1y = 0.0, s2y = 0.0;
  const bool has_d3 = (t & 7) != 7;   // col 4t+3 is not a patch boundary

#define LD(r) (*(const float4*)(base + (size_t)(r) * 1024))
#define DX(v) { float nx = __shfl_down((v).x, 1);                              \
    float d0 = fabsf((v).y-(v).x), d1 = fabsf((v).z-(v).y), d2 = fabsf((v).w-(v).z); \
    s1x += d0; s2x += (double)d0*d0;                                           \
    s1x += d1; s2x += (double)d1*d1;                                           \
    s1x += d2; s2x += (double)d2*d2;                                           \
    if (has_d3) { float d3 = fabsf(nx-(v).w); s1x += d3; s2x += (double)d3*d3; } }
#define DY(a,b) { float e0 = fabsf((b).x-(a).x), e1 = fabsf((b).y-(a).y),      \
                        e2 = fabsf((b).z-(a).z), e3 = fabsf((b).w-(a).w);      \
    s1y += e0; s2y += (double)e0*e0;                                           \
    s1y += e1; s2y += (double)e1*e1;                                           \
    s1y += e2; s2y += (double)e2*e2;                                           \
    s1y += e3; s2y += (double)e3*e3; }

  float4 v0 = LD(0);
  for (int r = 0; r < 32; r += 4) {
    float4 v1 = LD(r + 1);
    float4 v2 = LD(r + 2);
    float4 v3 = LD(r + 3);
    float4 v4;
    const bool more = (r + 4 < 32);
    if (more) v4 = LD(r + 4);
    DX(v0); DX(v1); DX(v2); DX(v3);
    DY(v0, v1); DY(v1, v2); DY(v2, v3);
    if (more) { DY(v3, v4); v0 = v4; }
  }
#undef LD
#undef DX
#undef DY

#pragma unroll
  for (int off = 4; off > 0; off >>= 1) {
    s1x += __shfl_down(s1x, off, 8);
    s2x += __shfl_down(s2x, off, 8);
    s1y += __shfl_down(s1y, off, 8);
    s2y += __shfl_down(s2y, off, 8);
  }
  if ((t & 7) == 0) {
    const int p = ph * 32 + (t >> 3);
    part[(size_t)(0 * NSLICE + s) * 1024 + p] = s1x;
    part[(size_t)(1 * NSLICE + s) * 1024 + p] = s2x;
    part[(size_t)(2 * NSLICE + s) * 1024 + p] = s1y;
    part[(size_t)(3 * NSLICE + s) * 1024 + p] = s2y;
  }
}

// --- K2: one block per patch. Wave w reduces quantity q=w over 48 slices; --
// all 192 loads in flight at once (one L3 round-trip), shfl tree reduce.
__global__ __launch_bounds__(256) void k_finalize(const double* __restrict__ part,
                                                  double* __restrict__ scores) {
  const int p    = blockIdx.x;
  const int t    = threadIdx.x;
  const int q    = t >> 6;          // wave index = quantity
  const int lane = t & 63;

  double v = 0.0;
  if (lane < NSLICE)
    v = part[(size_t)(q * NSLICE + lane) * 1024 + p];

#pragma unroll
  for (int off = 32; off > 0; off >>= 1) v += __shfl_down(v, off);

  __shared__ double S[4];
  if (lane == 0) S[q] = v;
  __syncthreads();

  if (t == 0) {
    const double N = 47616.0;  // 16*3*32*31
    double mx = S[0] / N, my = S[2] / N;
    double vx = (S[1] - S[0] * S[0] / N) / (N - 1.0);
    double vy = (S[3] - S[2] * S[2] / N) / (N - 1.0);
    scores[p] = 0.25 * (mx + my) * (vx + vy);
  }
}

// --- K3: stable rank; 8 lanes per candidate, 32 candidates per block. ------
// sel[0..8] = rich (ranks 1015..1023 asc), sel[9..17] = poor (ranks 0..8 asc).
__global__ __launch_bounds__(256) void k_rank(const double* __restrict__ scores,
                                              int* __restrict__ sel) {
  __shared__ double sc[1024];
  const int t = threadIdx.x;
  for (int i = t; i < 1024; i += 256) sc[i] = scores[i];
  __syncthreads();

  const int c = blockIdx.x * 32 + (t >> 3);
  const double mine = sc[c];
  int rank = 0;
  for (int j = (t & 7); j < 1024; j += 8) {
    double vj = sc[j];
    rank += (vj < mine) || (vj == mine && j < c);
  }
#pragma unroll
  for (int off = 4; off > 0; off >>= 1) rank += __shfl_down(rank, off, 8);
  if ((t & 7) == 0) {
    if (rank < 9)          sel[9 + rank]    = c;
    else if (rank >= 1015) sel[rank - 1015] = c;
  }
}

// --- K4: one block per (image, 8-row output strip). ------------------------
// R (<=6x96 src rows) -> H (x-bilerp, <=6x224) -> U (y-bilerp, 10x224)
// -> 3x3 SRM conv with zero padding.  (round-3 verbatim)
__global__ __launch_bounds__(256) void k_output(const float* __restrict__ x,
                                                const int* __restrict__ sel,
                                                float* __restrict__ out) {
  const int ty  = blockIdx.x;              // 0..27
  const int blk = blockIdx.y;              // 0..95 = set*48 + (b*3+c)
  const int set = blk / 48;
  const int bc  = blk % 48;
  const int y0  = ty * TILE;

  __shared__ int   i0t[224];
  __shared__ float frt[224];
  __shared__ float R[6][97];
  __shared__ float H[6][224];
  __shared__ float U[10][224];
  __shared__ int   selm[9];
  const int t = threadIdx.x;

  if (t < 9) selm[t] = sel[set * 9 + t];
  if (t < 224) {
    // src coord = (t+0.5)*96/224 - 0.5 = (3t-2)/7 ; edge renorm == clamp
    int num = 3 * t - 2;
    int i0, fr7;
    if (num < 0) { i0 = 0; fr7 = 0; }
    else {
      i0 = num / 7; fr7 = num - i0 * 7;
      if (i0 >= 95) { i0 = 95; fr7 = 0; }
    }
    i0t[t] = i0;
    frt[t] = (float)fr7 * (1.0f / 7.0f);
  }
  __syncthreads();

  const int Ylo   = max(y0 - 1, 0);
  const int Yhi   = min(y0 + TILE, 223);
  const int sy_lo = i0t[Ylo];
  const int sy_hi = min(i0t[Yhi] + 1, 95);
  const int nrows = sy_hi - sy_lo + 1;     // <= 6

  const float* src = x + (size_t)bc * IMG;
  for (int idx = t; idx < nrows * 96; idx += 256) {
    int ry = idx / 96, xx = idx - ry * 96;
    int sy = sy_lo + ry;
    int gr = sy >> 5, i = sy & 31;
    int gc = xx >> 5, j = xx & 31;
    int pidx = selm[gr * 3 + gc];
    R[ry][xx] = src[(size_t)((pidx >> 5) * 32 + i) * 1024 + (pidx & 31) * 32 + j];
  }
  __syncthreads();

  for (int idx = t; idx < nrows * 224; idx += 256) {
    int r = idx / 224, X = idx - r * 224;
    int ix0 = i0t[X], ix1 = min(ix0 + 1, 95);
    float fx = frt[X];
    float a = R[r][ix0], b = R[r][ix1];
    H[r][X] = a + fx * (b - a);
  }
  __syncthreads();

  for (int idx = t; idx < 10 * 224; idx += 256) {
    int yy = idx / 224, X = idx - yy * 224;
    int Y = y0 - 1 + yy;
    if ((unsigned)Y < 224u) {
      int a = i0t[Y] - sy_lo;
      int b = min(i0t[Y] + 1, 95) - sy_lo;
      float fy = frt[Y];
      float h0 = H[a][X], h1 = H[b][X];
      U[yy][X] = h0 + fy * (h1 - h0);
    }
  }
  __syncthreads();

  const float F[3][3] = {{-1.f, 3.f, -1.f}, {3.f, -8.f, 3.f}, {-1.f, 3.f, -1.f}};
  float* o = out + (size_t)blk * (224 * 224);
  for (int idx = t; idx < TILE * 224; idx += 256) {
    int yy = idx / 224;
    int xx = idx - yy * 224;
    int y  = y0 + yy;
    float acc = 0.f;
#pragma unroll
    for (int dy = 0; dy < 3; ++dy) {
      int Y = y + dy - 1;
      if ((unsigned)Y >= 224u) continue;
      const float* Ur = U[yy + dy];
#pragma unroll
      for (int dx = 0; dx < 3; ++dx) {
        int X = xx + dx - 1;
        if ((unsigned)X >= 224u) continue;
        acc += F[dy][dx] * Ur[X];
      }
    }
    o[(size_t)y * 224 + xx] = acc;
  }
}

extern "C" void kernel_launch(void* const* d_in, const int* in_sizes, int n_in,
                              void* d_out, int out_size, void* d_ws, size_t ws_size,
                              hipStream_t stream) {
  const float* x = (const float*)d_in[0];
  float* out = (float*)d_out;

  double* part   = (double*)d_ws;                          // 4*48*1024*8 = 1.5 MB
  double* scores = (double*)((char*)d_ws + 1572864);       // 8 KB
  int*    sel    = (int*)((char*)d_ws + 1581056);          // 72 B

  k_score   <<<dim3(32, 48), 256, 0, stream>>>(x, part);
  k_finalize<<<1024, 256, 0, stream>>>(part, scores);
  k_rank    <<<32, 256, 0, stream>>>(scores, sel);
  k_output  <<<dim3(28, 96), 256, 0, stream>>>(x, sel, out);
}

// Round 6
// 67.623 us; speedup vs baseline: 1.5947x; 1.0052x over previous
//
#include <hip/hip_runtime.h>

// ---------------------------------------------------------------------------
// TextureAnalysisModule: x (16,3,1024,1024) f32
//  k_score    : per-(patch,slice) |dx|,|dy| partial sums
//               (f32 row tree-sums -> one f64 add per quantity per row;
//                8-row unroll = 8 float4 loads in flight)
//  k_finalize : one block per patch; 192 parallel loads + shfl tree
//  k_rank     : stable rank-by-counting, scatter top9/bot9 indices
//  k_output   : gather patches -> R -> H (x-bilerp) -> U (y-bilerp) -> 3x3 SRM
//  out: (2,16,3,224,224) f32
// ---------------------------------------------------------------------------

#define NSLICE 48
#define IMG    1048576
#define TILE   8

// --- K1: one block per (patch-row, slice); contiguous 32x1024 strip. -------
__global__ __launch_bounds__(256) void k_score(const float* __restrict__ x,
                                               double* __restrict__ part) {
  const int ph = blockIdx.x;   // patch row 0..31
  const int s  = blockIdx.y;   // slice 0..47
  const int t  = threadIdx.x;
  const float* base = x + (size_t)s * IMG + (size_t)ph * 32768 + 4 * t;

  double s1x = 0.0, s2x = 0.0, s1y = 0.0, s2y = 0.0;
  const bool has_d3 = (t & 7) != 7;   // col 4t+3 is not a patch boundary

#define LD(r) (*(const float4*)(base + (size_t)(r) * 1024))
  // f32 tree-sum per row, single f64 add per quantity per row.
#define DX(v) { float nx = __shfl_down((v).x, 1);                              \
    float d0 = fabsf((v).y-(v).x), d1 = fabsf((v).z-(v).y),                    \
          d2 = fabsf((v).w-(v).z);                                             \
    float d3 = has_d3 ? fabsf(nx-(v).w) : 0.f;                                 \
    s1x += (double)((d0+d1)+(d2+d3));                                          \
    s2x += (double)((d0*d0+d1*d1)+(d2*d2+d3*d3)); }
#define DY(a,b) { float e0 = fabsf((b).x-(a).x), e1 = fabsf((b).y-(a).y),      \
                        e2 = fabsf((b).z-(a).z), e3 = fabsf((b).w-(a).w);      \
    s1y += (double)((e0+e1)+(e2+e3));                                          \
    s2y += (double)((e0*e0+e1*e1)+(e2*e2+e3*e3)); }

  float4 v0 = LD(0);
  for (int r = 0; r < 32; r += 8) {
    float4 w1 = LD(r + 1), w2 = LD(r + 2), w3 = LD(r + 3), w4 = LD(r + 4);
    float4 w5 = LD(r + 5), w6 = LD(r + 6), w7 = LD(r + 7);
    float4 w8;
    const bool more = (r + 8 < 32);
    if (more) w8 = LD(r + 8);
    DX(v0); DX(w1); DX(w2); DX(w3); DX(w4); DX(w5); DX(w6); DX(w7);
    DY(v0, w1); DY(w1, w2); DY(w2, w3); DY(w3, w4);
    DY(w4, w5); DY(w5, w6); DY(w6, w7);
    if (more) { DY(w7, w8); v0 = w8; }
  }
#undef LD
#undef DX
#undef DY

  // reduce within each 8-lane group (one patch per group)
#pragma unroll
  for (int off = 4; off > 0; off >>= 1) {
    s1x += __shfl_down(s1x, off, 8);
    s2x += __shfl_down(s2x, off, 8);
    s1y += __shfl_down(s1y, off, 8);
    s2y += __shfl_down(s2y, off, 8);
  }
  if ((t & 7) == 0) {
    const int p = ph * 32 + (t >> 3);
    part[(size_t)(0 * NSLICE + s) * 1024 + p] = s1x;
    part[(size_t)(1 * NSLICE + s) * 1024 + p] = s2x;
    part[(size_t)(2 * NSLICE + s) * 1024 + p] = s1y;
    part[(size_t)(3 * NSLICE + s) * 1024 + p] = s2y;
  }
}

// --- K2: one block per patch. Wave w reduces quantity q=w over 48 slices; --
// all 192 loads in flight at once (one L3 round-trip), shfl tree reduce.
__global__ __launch_bounds__(256) void k_finalize(const double* __restrict__ part,
                                                  double* __restrict__ scores) {
  const int p    = blockIdx.x;
  const int t    = threadIdx.x;
  const int q    = t >> 6;          // wave index = quantity
  const int lane = t & 63;

  double v = 0.0;
  if (lane < NSLICE)
    v = part[(size_t)(q * NSLICE + lane) * 1024 + p];

#pragma unroll
  for (int off = 32; off > 0; off >>= 1) v += __shfl_down(v, off);

  __shared__ double S[4];
  if (lane == 0) S[q] = v;
  __syncthreads();

  if (t == 0) {
    const double N = 47616.0;  // 16*3*32*31
    double mx = S[0] / N, my = S[2] / N;
    double vx = (S[1] - S[0] * S[0] / N) / (N - 1.0);
    double vy = (S[3] - S[2] * S[2] / N) / (N - 1.0);
    scores[p] = 0.25 * (mx + my) * (vx + vy);
  }
}

// --- K3: stable rank; 8 lanes per candidate, 32 candidates per block. ------
// sel[0..8] = rich (ranks 1015..1023 asc), sel[9..17] = poor (ranks 0..8 asc).
__global__ __launch_bounds__(256) void k_rank(const double* __restrict__ scores,
                                              int* __restrict__ sel) {
  __shared__ double sc[1024];
  const int t = threadIdx.x;
  for (int i = t; i < 1024; i += 256) sc[i] = scores[i];
  __syncthreads();

  const int c = blockIdx.x * 32 + (t >> 3);
  const double mine = sc[c];
  int rank = 0;
  for (int j = (t & 7); j < 1024; j += 8) {
    double vj = sc[j];
    rank += (vj < mine) || (vj == mine && j < c);
  }
#pragma unroll
  for (int off = 4; off > 0; off >>= 1) rank += __shfl_down(rank, off, 8);
  if ((t & 7) == 0) {
    if (rank < 9)          sel[9 + rank]    = c;
    else if (rank >= 1015) sel[rank - 1015] = c;
  }
}

// --- K4: one block per (image, 8-row output strip). ------------------------
// R (<=6x96 src rows) -> H (x-bilerp, <=6x224) -> U (y-bilerp, 10x224)
// -> 3x3 SRM conv with zero padding.
__global__ __launch_bounds__(256) void k_output(const float* __restrict__ x,
                                                const int* __restrict__ sel,
                                                float* __restrict__ out) {
  const int ty  = blockIdx.x;              // 0..27
  const int blk = blockIdx.y;              // 0..95 = set*48 + (b*3+c)
  const int set = blk / 48;
  const int bc  = blk % 48;
  const int y0  = ty * TILE;

  __shared__ int   i0t[224];
  __shared__ float frt[224];
  __shared__ float R[6][97];
  __shared__ float H[6][224];
  __shared__ float U[10][224];
  __shared__ int   selm[9];
  const int t = threadIdx.x;

  if (t < 9) selm[t] = sel[set * 9 + t];
  if (t < 224) {
    // src coord = (t+0.5)*96/224 - 0.5 = (3t-2)/7 ; edge renorm == clamp
    int num = 3 * t - 2;
    int i0, fr7;
    if (num < 0) { i0 = 0; fr7 = 0; }
    else {
      i0 = num / 7; fr7 = num - i0 * 7;
      if (i0 >= 95) { i0 = 95; fr7 = 0; }
    }
    i0t[t] = i0;
    frt[t] = (float)fr7 * (1.0f / 7.0f);
  }
  __syncthreads();

  const int Ylo   = max(y0 - 1, 0);
  const int Yhi   = min(y0 + TILE, 223);
  const int sy_lo = i0t[Ylo];
  const int sy_hi = min(i0t[Yhi] + 1, 95);
  const int nrows = sy_hi - sy_lo + 1;     // <= 6

  const float* src = x + (size_t)bc * IMG;
  for (int idx = t; idx < nrows * 96; idx += 256) {
    int ry = idx / 96, xx = idx - ry * 96;
    int sy = sy_lo + ry;
    int gr = sy >> 5, i = sy & 31;
    int gc = xx >> 5, j = xx & 31;
    int pidx = selm[gr * 3 + gc];
    R[ry][xx] = src[(size_t)((pidx >> 5) * 32 + i) * 1024 + (pidx & 31) * 32 + j];
  }
  __syncthreads();

  for (int idx = t; idx < nrows * 224; idx += 256) {
    int r = idx / 224, X = idx - r * 224;
    int ix0 = i0t[X], ix1 = min(ix0 + 1, 95);
    float fx = frt[X];
    float a = R[r][ix0], b = R[r][ix1];
    H[r][X] = a + fx * (b - a);
  }
  __syncthreads();

  for (int idx = t; idx < 10 * 224; idx += 256) {
    int yy = idx / 224, X = idx - yy * 224;
    int Y = y0 - 1 + yy;
    if ((unsigned)Y < 224u) {
      int a = i0t[Y] - sy_lo;
      int b = min(i0t[Y] + 1, 95) - sy_lo;
      float fy = frt[Y];
      float h0 = H[a][X], h1 = H[b][X];
      U[yy][X] = h0 + fy * (h1 - h0);
    }
  }
  __syncthreads();

  const float F[3][3] = {{-1.f, 3.f, -1.f}, {3.f, -8.f, 3.f}, {-1.f, 3.f, -1.f}};
  float* o = out + (size_t)blk * (224 * 224);
  for (int idx = t; idx < TILE * 224; idx += 256) {
    int yy = idx / 224;
    int xx = idx - yy * 224;
    int y  = y0 + yy;
    float acc = 0.f;
#pragma unroll
    for (int dy = 0; dy < 3; ++dy) {
      int Y = y + dy - 1;
      if ((unsigned)Y >= 224u) continue;
      const float* Ur = U[yy + dy];
#pragma unroll
      for (int dx = 0; dx < 3; ++dx) {
        int X = xx + dx - 1;
        if ((unsigned)X >= 224u) continue;
        acc += F[dy][dx] * Ur[X];
      }
    }
    o[(size_t)y * 224 + xx] = acc;
  }
}

extern "C" void kernel_launch(void* const* d_in, const int* in_sizes, int n_in,
                              void* d_out, int out_size, void* d_ws, size_t ws_size,
                              hipStream_t stream) {
  const float* x = (const float*)d_in[0];
  float* out = (float*)d_out;

  double* part   = (double*)d_ws;                          // 4*48*1024*8 = 1.5 MB
  double* scores = (double*)((char*)d_ws + 1572864);       // 8 KB
  int*    sel    = (int*)((char*)d_ws + 1581056);          // 72 B

  k_score   <<<dim3(32, 48), 256, 0, stream>>>(x, part);
  k_finalize<<<1024, 256, 0, stream>>>(part, scores);
  k_rank    <<<32, 256, 0, stream>>>(scores, sel);
  k_output  <<<dim3(28, 96), 256, 0, stream>>>(x, sel, out);
}